// Round 2
// baseline (527.305 us; speedup 1.0000x reference)
//
#include <hip/hip_runtime.h>
#include <hip/hip_bf16.h>
#include <cstdint>

// Problem constants (fixed by the reference setup)
#define BB 16      // batch
#define NN 2048    // tokens
#define DD 1024    // model dim
#define HH 8       // heads
#define AA 8       // atlas tokens
#define CC 128     // 2H * A score channels
#define DH 64      // half-head dim d
#define TD 128     // 2d
#define LAMBDA_INIT 0.8f
#define EPS_ 1e-5f

// Workspace layout (float offsets)
static constexpr size_t OFF_QPROJ = 0;                   // 8*1024
static constexpr size_t OFF_MT    = 8192;                // 1024*128 (M transposed [j][c])
static constexpr size_t OFF_LAM   = OFF_MT + 131072;     // 1 (padded to 64)
static constexpr size_t OFF_WOH   = OFF_LAM + 64;        // 1024
static constexpr size_t OFF_SC    = OFF_WOH + 1024;      // 16*128*2048  (reused as yp[32][128][1024] later)
static constexpr size_t OFF_DIFF  = OFF_SC + 4194304;    // 16*64*2048
static constexpr size_t OFF_AGG   = OFF_DIFF + 2097152;  // 2 * 16*64*1024 (n-split partials)
// yp reuses OFF_SC: scores is dead after k_softdiff; sizes match exactly (4194304 floats).

// ---------------- setup kernels (tiny) ----------------

// qproj[a][j] = sum_i atlas_q[a][i] * Wq[i][j]
__global__ __launch_bounds__(256) void k_qproj(const float* __restrict__ atlas_q,
                                               const float* __restrict__ Wq,
                                               float* __restrict__ qproj) {
    int a = blockIdx.x;                       // 8
    int j = blockIdx.y * 256 + threadIdx.x;   // 4*256
    const float* aq = atlas_q + a * DD;
    float acc = 0.f;
#pragma unroll 8
    for (int i = 0; i < DD; ++i)
        acc = fmaf(aq[i], Wq[(size_t)i * DD + j], acc);
    qproj[a * DD + j] = acc;
}

// Mt[j][c] = d^-0.5 * sum_t qproj[a][h2*64+t] * Wk[j][h2*64+t],  c = h2*8 + a
__global__ __launch_bounds__(128) void k_mt(const float* __restrict__ qproj,
                                            const float* __restrict__ Wk,
                                            float* __restrict__ Mt) {
    int j = blockIdx.x;          // 1024
    int c = threadIdx.x;         // 128
    int h2 = c >> 3, a = c & 7;
    const float* qp = qproj + a * DD + h2 * DH;
    const float* wk = Wk + (size_t)j * DD + h2 * DH;
    float acc = 0.f;
#pragma unroll
    for (int t = 0; t < DH; t += 4) {
        float4 q4 = *(const float4*)(qp + t);
        float4 w4 = *(const float4*)(wk + t);
        acc += q4.x * w4.x + q4.y * w4.y + q4.z * w4.z + q4.w * w4.w;
    }
    Mt[(size_t)j * CC + c] = acc * 0.125f;
}

// lam = exp(lq1.lk1) - exp(lq2.lk2) + 0.8
__global__ void k_lam(const float* __restrict__ lq1, const float* __restrict__ lk1,
                      const float* __restrict__ lq2, const float* __restrict__ lk2,
                      float* __restrict__ lam) {
    int t = threadIdx.x;  // 64
    float p1 = lq1[t] * lk1[t];
    float p2 = lq2[t] * lk2[t];
#pragma unroll
    for (int off = 32; off; off >>= 1) {
        p1 += __shfl_down(p1, off);
        p2 += __shfl_down(p2, off);
    }
    if (t == 0) *lam = expf(p1) - expf(p2) + LAMBDA_INIT;
}

// woh[i] = sum_j Wo[i][j] * Whead[j]
__global__ __launch_bounds__(256) void k_wohead(const float* __restrict__ Wo,
                                                const float* __restrict__ Whead,
                                                float* __restrict__ woh) {
    int i = blockIdx.x * 256 + threadIdx.x;   // 4*256
    const float* row = Wo + (size_t)i * DD;
    float acc = 0.f;
#pragma unroll 4
    for (int j = 0; j < DD; j += 4) {
        float4 r = *(const float4*)(row + j);
        float4 w = *(const float4*)(Whead + j);
        acc += r.x * w.x + r.y * w.y + r.z * w.z + r.w * w.w;
    }
    woh[i] = acc;
}

// ---------------- main pass 1: scores = X @ Mt  ([B,C,N] layout) ----------------
__global__ __launch_bounds__(256) void k_scores(const float* __restrict__ x,
                                                const float* __restrict__ Mt,
                                                float* __restrict__ scores) {
    __shared__ float Xs[64][64];   // [jj][n] transposed
    __shared__ float Ms[64][128];  // [jj][c]
    int b = blockIdx.x;            // 16
    int n0 = blockIdx.y * 64;      // 32 tiles
    int tid = threadIdx.x;
    int tn = tid & 15;             // n group (4 n each)
    int tc = tid >> 4;             // c group (8 c each)
    float acc[4][8] = {};
    const float* xb = x + ((size_t)b * NN + n0) * DD;
    for (int j0 = 0; j0 < DD; j0 += 64) {
        // stage X tile transposed: Xs[jj][row]
#pragma unroll
        for (int t = 0; t < 4; ++t) {
            int f4 = tid + t * 256;
            int row = f4 >> 4, j4 = (f4 & 15) * 4;
            float4 v = *(const float4*)(xb + (size_t)row * DD + j0 + j4);
            Xs[j4 + 0][row] = v.x; Xs[j4 + 1][row] = v.y;
            Xs[j4 + 2][row] = v.z; Xs[j4 + 3][row] = v.w;
        }
        // stage M tile: Ms[jj][c] (already transposed in global)
#pragma unroll
        for (int t = 0; t < 8; ++t) {
            int f4 = tid + t * 256;
            int jj = f4 >> 5, c4 = (f4 & 31) * 4;
            *(float4*)(&Ms[jj][c4]) = *(const float4*)(Mt + (size_t)(j0 + jj) * CC + c4);
        }
        __syncthreads();
#pragma unroll
        for (int jj = 0; jj < 64; ++jj) {
            float4 xv4 = *(const float4*)(&Xs[jj][tn * 4]);
            float4 m0 = *(const float4*)(&Ms[jj][tc * 8]);
            float4 m1 = *(const float4*)(&Ms[jj][tc * 8 + 4]);
            float xv[4] = {xv4.x, xv4.y, xv4.z, xv4.w};
            float mv[8] = {m0.x, m0.y, m0.z, m0.w, m1.x, m1.y, m1.z, m1.w};
#pragma unroll
            for (int i = 0; i < 4; ++i)
#pragma unroll
                for (int k = 0; k < 8; ++k)
                    acc[i][k] = fmaf(xv[i], mv[k], acc[i][k]);
        }
        __syncthreads();
    }
#pragma unroll
    for (int k = 0; k < 8; ++k) {
        int c = tc * 8 + k;
        float4 o = {acc[0][k], acc[1][k], acc[2][k], acc[3][k]};
        *(float4*)(scores + ((size_t)b * CC + c) * NN + n0 + tn * 4) = o;
    }
}

// ---------------- pass 2: softmax rows + differential combine ----------------
__global__ __launch_bounds__(256) void k_softdiff(const float* __restrict__ scores,
                                                  const float* __restrict__ lam_p,
                                                  float* __restrict__ diff) {
    int blk = blockIdx.x;   // b*64 + h*8 + a
    int b = blk >> 6, h = (blk >> 3) & 7, a = blk & 7;
    int tid = threadIdx.x;
    const float* r0 = scores + ((size_t)b * CC + (2 * h) * AA + a) * NN;
    const float* r1 = scores + ((size_t)b * CC + (2 * h + 1) * AA + a) * NN;
    float v0[8], v1[8];
    float m0 = -1e30f, m1 = -1e30f;
#pragma unroll
    for (int k = 0; k < 8; ++k) {
        v0[k] = r0[tid + k * 256];
        v1[k] = r1[tid + k * 256];
        m0 = fmaxf(m0, v0[k]); m1 = fmaxf(m1, v1[k]);
    }
    __shared__ float redm[4][2];
    __shared__ float reds[4][2];
    int w = tid >> 6, lane = tid & 63;
#pragma unroll
    for (int off = 32; off; off >>= 1) {
        m0 = fmaxf(m0, __shfl_down(m0, off));
        m1 = fmaxf(m1, __shfl_down(m1, off));
    }
    if (lane == 0) { redm[w][0] = m0; redm[w][1] = m1; }
    __syncthreads();
    m0 = fmaxf(fmaxf(redm[0][0], redm[1][0]), fmaxf(redm[2][0], redm[3][0]));
    m1 = fmaxf(fmaxf(redm[0][1], redm[1][1]), fmaxf(redm[2][1], redm[3][1]));
    float s0 = 0.f, s1 = 0.f;
#pragma unroll
    for (int k = 0; k < 8; ++k) {
        v0[k] = expf(v0[k] - m0); s0 += v0[k];
        v1[k] = expf(v1[k] - m1); s1 += v1[k];
    }
#pragma unroll
    for (int off = 32; off; off >>= 1) {
        s0 += __shfl_down(s0, off);
        s1 += __shfl_down(s1, off);
    }
    if (lane == 0) { reds[w][0] = s0; reds[w][1] = s1; }
    __syncthreads();
    s0 = reds[0][0] + reds[1][0] + reds[2][0] + reds[3][0];
    s1 = reds[0][1] + reds[1][1] + reds[2][1] + reds[3][1];
    float lam = *lam_p;
    float inv0 = 1.f / s0;
    float inv1 = lam / s1;
    float* drow = diff + ((size_t)(b * HH + h) * AA + a) * NN;
#pragma unroll
    for (int k = 0; k < 8; ++k)
        drow[tid + k * 256] = v0[k] * inv0 - v1[k] * inv1;
}

// ---------------- pass 3: aggp[s][b][r][j] = sum_{n in half s} diff * x ----------------
// agg row r = a*8 + h ; diff row rp = h*8 + a
__global__ __launch_bounds__(256) void k_agg(const float* __restrict__ x,
                                             const float* __restrict__ diff,
                                             float* __restrict__ aggp) {
    __shared__ float Ds[64][64];   // [nn][r] transposed
    __shared__ float Xs[64][64];   // [nn][jj]
    int b = blockIdx.x;            // 16
    int jt = blockIdx.y;           // 16
    int s = blockIdx.z;            // 2
    int j0 = jt * 64;
    int tid = threadIdx.x;
    int tj = tid & 15;             // 4 j each
    int tr = tid >> 4;             // 4 r each
    float acc[4][4] = {};
    for (int nc = 0; nc < 1024; nc += 64) {
        int n0 = s * 1024 + nc;
#pragma unroll
        for (int t = 0; t < 4; ++t) {
            int f4 = tid + t * 256;
            int r = f4 >> 4, n4 = (f4 & 15) * 4;
            int rp = ((r & 7) << 3) | (r >> 3);
            float4 v = *(const float4*)(diff + ((size_t)b * 64 + rp) * NN + n0 + n4);
            Ds[n4 + 0][r] = v.x; Ds[n4 + 1][r] = v.y;
            Ds[n4 + 2][r] = v.z; Ds[n4 + 3][r] = v.w;
        }
#pragma unroll
        for (int t = 0; t < 4; ++t) {
            int f4 = tid + t * 256;
            int nn = f4 >> 4, j4 = (f4 & 15) * 4;
            *(float4*)(&Xs[nn][j4]) = *(const float4*)(x + ((size_t)b * NN + n0 + nn) * DD + j0 + j4);
        }
        __syncthreads();
#pragma unroll
        for (int nn = 0; nn < 64; ++nn) {
            float4 dv4 = *(const float4*)(&Ds[nn][tr * 4]);
            float4 xv4 = *(const float4*)(&Xs[nn][tj * 4]);
            float dv[4] = {dv4.x, dv4.y, dv4.z, dv4.w};
            float xv[4] = {xv4.x, xv4.y, xv4.z, xv4.w};
#pragma unroll
            for (int i = 0; i < 4; ++i)
#pragma unroll
                for (int k = 0; k < 4; ++k)
                    acc[i][k] = fmaf(dv[i], xv[k], acc[i][k]);
        }
        __syncthreads();
    }
#pragma unroll
    for (int i = 0; i < 4; ++i) {
        float4 o = {acc[i][0], acc[i][1], acc[i][2], acc[i][3]};
        *(float4*)(aggp + (((size_t)s * BB + b) * 64 + tr * 4 + i) * DD + j0 + tj * 4) = o;
    }
}

// ---------------- pass 4a: Y partials  yp[ks][row=b*8+a][p=h*128+e] over j-chunk ks ----------------
__global__ __launch_bounds__(256) void k_yp(const float* __restrict__ aggp,
                                            const float* __restrict__ Wv,
                                            float* __restrict__ yp) {
    __shared__ float Wvs[32][128];  // [jj][e]
    __shared__ float As[32][128];   // [jj][row]
    int h = blockIdx.x;     // 8
    int ks = blockIdx.y;    // 32
    int j0 = ks * 32;
    int tid = threadIdx.x;
    int tr = tid >> 4;      // 8 rows each
    int te = tid & 15;      // 8 e each
#pragma unroll
    for (int t = 0; t < 4; ++t) {
        int f4 = tid + t * 256;
        int jj = f4 >> 5, e4 = (f4 & 31) * 4;
        *(float4*)(&Wvs[jj][e4]) = *(const float4*)(Wv + (size_t)(j0 + jj) * DD + h * TD + e4);
    }
#pragma unroll
    for (int t = 0; t < 4; ++t) {
        int f4 = tid + t * 256;
        int row = f4 >> 3;        // 0..127 (b*8+a)
        int j4 = (f4 & 7) * 4;    // 0..28
        int b_ = row >> 3, a_ = row & 7;
        size_t base = (((size_t)b_ * 64) + a_ * 8 + h) * DD + j0 + j4;
        float4 u = *(const float4*)(aggp + base);
        float4 v = *(const float4*)(aggp + (size_t)BB * 64 * DD + base);
        As[j4 + 0][row] = u.x + v.x; As[j4 + 1][row] = u.y + v.y;
        As[j4 + 2][row] = u.z + v.z; As[j4 + 3][row] = u.w + v.w;
    }
    __syncthreads();
    float acc[8][8] = {};
#pragma unroll
    for (int jj = 0; jj < 32; ++jj) {
        float4 a0 = *(const float4*)(&As[jj][tr * 8]);
        float4 a1 = *(const float4*)(&As[jj][tr * 8 + 4]);
        float4 w0 = *(const float4*)(&Wvs[jj][te * 8]);
        float4 w1 = *(const float4*)(&Wvs[jj][te * 8 + 4]);
        float av[8] = {a0.x, a0.y, a0.z, a0.w, a1.x, a1.y, a1.z, a1.w};
        float wv[8] = {w0.x, w0.y, w0.z, w0.w, w1.x, w1.y, w1.z, w1.w};
#pragma unroll
        for (int i = 0; i < 8; ++i)
#pragma unroll
            for (int k = 0; k < 8; ++k)
                acc[i][k] = fmaf(av[i], wv[k], acc[i][k]);
    }
    // store: p = h*128 + e  (h folded into the column index — fixes the R0 race)
#pragma unroll
    for (int i = 0; i < 8; ++i) {
        float4 o0 = {acc[i][0], acc[i][1], acc[i][2], acc[i][3]};
        float4 o1 = {acc[i][4], acc[i][5], acc[i][6], acc[i][7]};
        float* dst = yp + ((size_t)ks * 128 + tr * 8 + i) * DD + h * TD + te * 8;
        *(float4*)dst = o0;
        *(float4*)(dst + 4) = o1;
    }
}

// ---------------- pass 4b: reduce partials, RMSNorm, dot with wo_head ----------------
__global__ __launch_bounds__(256) void k_logits(const float* __restrict__ yp,
                                                const float* __restrict__ rms_w,
                                                const float* __restrict__ woh,
                                                float* __restrict__ logits) {
    int row = blockIdx.x;   // 128 = b*8+a
    int tid = threadIdx.x;
    __shared__ float hss[8];
    __shared__ float red[4];
    if (tid < 8) hss[tid] = 0.f;
    __syncthreads();
    float y[4];
#pragma unroll
    for (int k = 0; k < 4; ++k) {
        int p = tid + k * 256;
        float acc = 0.f;
#pragma unroll 8
        for (int ks = 0; ks < 32; ++ks)
            acc += yp[((size_t)ks * 128 + row) * DD + p];   // stride DD=1024 (fixes R0 misread)
        y[k] = acc;
        atomicAdd(&hss[p >> 7], acc * acc);
    }
    __syncthreads();
    float val = 0.f;
#pragma unroll
    for (int k = 0; k < 4; ++k) {
        int p = tid + k * 256;
        int h = p >> 7, e = p & 127;
        float rs = rsqrtf(hss[h] * (1.f / 128.f) + EPS_);
        val += y[k] * rs * rms_w[e] * (1.f - LAMBDA_INIT) * woh[p];
    }
#pragma unroll
    for (int off = 32; off; off >>= 1) val += __shfl_down(val, off);
    int w = tid >> 6, lane = tid & 63;
    if (lane == 0) red[w] = val;
    __syncthreads();
    if (tid == 0) logits[row] = red[0] + red[1] + red[2] + red[3];
}

extern "C" void kernel_launch(void* const* d_in, const int* in_sizes, int n_in,
                              void* d_out, int out_size, void* d_ws, size_t ws_size,
                              hipStream_t stream) {
    (void)in_sizes; (void)n_in; (void)out_size; (void)ws_size;
    const float* x       = (const float*)d_in[0];
    const float* atlas_q = (const float*)d_in[1];
    const float* Wq      = (const float*)d_in[2];
    const float* Wk      = (const float*)d_in[3];
    const float* Wv      = (const float*)d_in[4];
    const float* Wo      = (const float*)d_in[5];
    const float* rms_w   = (const float*)d_in[6];
    const float* Whead   = (const float*)d_in[7];
    const float* lq1     = (const float*)d_in[8];
    const float* lk1     = (const float*)d_in[9];
    const float* lq2     = (const float*)d_in[10];
    const float* lk2     = (const float*)d_in[11];
    float* out = (float*)d_out;
    float* ws  = (float*)d_ws;

    float* qproj  = ws + OFF_QPROJ;
    float* Mt     = ws + OFF_MT;
    float* lam    = ws + OFF_LAM;
    float* woh    = ws + OFF_WOH;
    float* scores = ws + OFF_SC;
    float* diff   = ws + OFF_DIFF;
    float* aggp   = ws + OFF_AGG;
    float* yp     = ws + OFF_SC;   // reuse scores region (dead after k_softdiff); sizes match

    hipLaunchKernelGGL(k_qproj,    dim3(8, 4),     dim3(256), 0, stream, atlas_q, Wq, qproj);
    hipLaunchKernelGGL(k_lam,      dim3(1),        dim3(64),  0, stream, lq1, lk1, lq2, lk2, lam);
    hipLaunchKernelGGL(k_wohead,   dim3(4),        dim3(256), 0, stream, Wo, Whead, woh);
    hipLaunchKernelGGL(k_mt,       dim3(1024),     dim3(128), 0, stream, qproj, Wk, Mt);
    hipLaunchKernelGGL(k_scores,   dim3(16, 32),   dim3(256), 0, stream, x, Mt, scores);
    hipLaunchKernelGGL(k_softdiff, dim3(1024),     dim3(256), 0, stream, scores, lam, diff);
    hipLaunchKernelGGL(k_agg,      dim3(16, 16, 2),dim3(256), 0, stream, x, diff, aggp);
    hipLaunchKernelGGL(k_yp,       dim3(8, 32),    dim3(256), 0, stream, aggp, Wv, yp);
    hipLaunchKernelGGL(k_logits,   dim3(128),      dim3(256), 0, stream, yp, rms_w, woh, out);
}

// Round 3
// 453.167 us; speedup vs baseline: 1.1636x; 1.1636x over previous
//
#include <hip/hip_runtime.h>
#include <hip/hip_bf16.h>
#include <cstdint>

#define BB 16      // batch
#define NN 2048    // tokens
#define DD 1024    // model dim
#define HH 8       // heads
#define AA 8       // atlas tokens
#define CC 128     // 2H * A score channels
#define DH 64      // half-head dim d
#define TD 128     // 2d
#define LAMBDA_INIT 0.8f
#define EPS_ 1e-5f

typedef short short8 __attribute__((ext_vector_type(8)));
typedef float f32x4  __attribute__((ext_vector_type(4)));

static __device__ __forceinline__ ushort f2bf(float f) {
    uint32_t u = __float_as_uint(f);
    return (ushort)((u + 0x8000u) >> 16);   // round-to-nearest (ties away) bf16
}

// Workspace layout (float offsets)
static constexpr size_t OFF_QPROJ = 0;                       // 8192
static constexpr size_t OFF_M2    = 8192;                    // 65536 floats worth (128*1024 ushort)
static constexpr size_t OFF_LAM   = OFF_M2 + 65536;          // 64
static constexpr size_t OFF_WOH   = OFF_LAM + 64;            // 1024
static constexpr size_t OFF_SC    = OFF_WOH + 1024;          // 4194304 (scores fp32; reused as yp later)
static constexpr size_t OFF_DIFFB = OFF_SC + 4194304;        // 1048576 floats worth (16*64*2048 ushort)
static constexpr size_t OFF_AGG   = OFF_DIFFB + 1048576;     // 2097152

// ---------------- setup kernels ----------------

__global__ __launch_bounds__(256) void k_qproj(const float* __restrict__ atlas_q,
                                               const float* __restrict__ Wq,
                                               float* __restrict__ qproj) {
    int a = blockIdx.x;
    int j = blockIdx.y * 256 + threadIdx.x;
    const float* aq = atlas_q + a * DD;
    float acc = 0.f;
#pragma unroll 8
    for (int i = 0; i < DD; ++i)
        acc = fmaf(aq[i], Wq[(size_t)i * DD + j], acc);
    qproj[a * DD + j] = acc;
}

// M2[c][j] (bf16) = d^-0.5 * sum_t qproj[a][h2*64+t] * Wk[j][h2*64+t],  c = h2*8 + a
__global__ __launch_bounds__(256) void k_m2(const float* __restrict__ qproj,
                                            const float* __restrict__ Wk,
                                            ushort* __restrict__ M2) {
    int c = blockIdx.x;           // 128
    int h2 = c >> 3, a = c & 7;
    const float* qp = qproj + a * DD + h2 * DH;
    int tid = threadIdx.x;
#pragma unroll
    for (int it = 0; it < 4; ++it) {
        int j = it * 256 + tid;
        const float* wk = Wk + (size_t)j * DD + h2 * DH;
        float acc = 0.f;
#pragma unroll
        for (int t = 0; t < DH; t += 4) {
            float4 q4 = *(const float4*)(qp + t);
            float4 w4 = *(const float4*)(wk + t);
            acc += q4.x * w4.x + q4.y * w4.y + q4.z * w4.z + q4.w * w4.w;
        }
        M2[(size_t)c * DD + j] = f2bf(acc * 0.125f);
    }
}

__global__ void k_lam(const float* __restrict__ lq1, const float* __restrict__ lk1,
                      const float* __restrict__ lq2, const float* __restrict__ lk2,
                      float* __restrict__ lam) {
    int t = threadIdx.x;  // 64
    float p1 = lq1[t] * lk1[t];
    float p2 = lq2[t] * lk2[t];
#pragma unroll
    for (int off = 32; off; off >>= 1) {
        p1 += __shfl_down(p1, off);
        p2 += __shfl_down(p2, off);
    }
    if (t == 0) *lam = expf(p1) - expf(p2) + LAMBDA_INIT;
}

__global__ __launch_bounds__(256) void k_wohead(const float* __restrict__ Wo,
                                                const float* __restrict__ Whead,
                                                float* __restrict__ woh) {
    int i = blockIdx.x * 256 + threadIdx.x;
    const float* row = Wo + (size_t)i * DD;
    float acc = 0.f;
#pragma unroll 4
    for (int j = 0; j < DD; j += 4) {
        float4 r = *(const float4*)(row + j);
        float4 w = *(const float4*)(Whead + j);
        acc += r.x * w.x + r.y * w.y + r.z * w.z + r.w * w.w;
    }
    woh[i] = acc;
}

// ---------------- pass 1: scores[b][c][n] = X @ M2^T via MFMA (no LDS) ----------------
// block: 256 thr = 4 waves, covers 64 n x 128 c; grid (16 b, 32 nt)
__global__ __launch_bounds__(256) void k_scores(const float* __restrict__ x,
                                                const ushort* __restrict__ M2,
                                                float* __restrict__ scores) {
    int b = blockIdx.x, nt = blockIdx.y;
    int tid = threadIdx.x;
    int lane = tid & 63, w = tid >> 6;
    int l15 = lane & 15, kg = lane >> 4;      // A row / k-group
    int n = nt * 64 + w * 16 + l15;
    const float* xr = x + ((size_t)b * NN + n) * DD + kg * 8;

    f32x4 acc[8] = {};
    for (int j0 = 0; j0 < DD; j0 += 32) {
        float4 a0 = *(const float4*)(xr + j0);
        float4 a1 = *(const float4*)(xr + j0 + 4);
        short8 av;
        av[0] = (short)f2bf(a0.x); av[1] = (short)f2bf(a0.y);
        av[2] = (short)f2bf(a0.z); av[3] = (short)f2bf(a0.w);
        av[4] = (short)f2bf(a1.x); av[5] = (short)f2bf(a1.y);
        av[6] = (short)f2bf(a1.z); av[7] = (short)f2bf(a1.w);
        uint4 bu[8];
#pragma unroll
        for (int ct = 0; ct < 8; ++ct)
            bu[ct] = *(const uint4*)(M2 + ((size_t)(ct * 16 + l15)) * DD + j0 + kg * 8);
#pragma unroll
        for (int ct = 0; ct < 8; ++ct)
            acc[ct] = __builtin_amdgcn_mfma_f32_16x16x32_bf16(
                av, __builtin_bit_cast(short8, bu[ct]), acc[ct], 0, 0, 0);
    }
    // D: col=lane&15 -> c, row=(lane>>4)*4+reg -> n ; 4 consecutive n per lane = float4
#pragma unroll
    for (int ct = 0; ct < 8; ++ct) {
        float4 o = {acc[ct][0], acc[ct][1], acc[ct][2], acc[ct][3]};
        *(float4*)(scores + ((size_t)b * CC + ct * 16 + l15) * NN + nt * 64 + w * 16 + kg * 4) = o;
    }
}

// ---------------- pass 2: softmax rows + differential combine -> bf16 diffb[b][a*8+h][n] ----------------
__global__ __launch_bounds__(256) void k_softdiff(const float* __restrict__ scores,
                                                  const float* __restrict__ lam_p,
                                                  ushort* __restrict__ diffb) {
    int blk = blockIdx.x;   // b*64 + h*8 + a
    int b = blk >> 6, h = (blk >> 3) & 7, a = blk & 7;
    int tid = threadIdx.x;
    const float* r0 = scores + ((size_t)b * CC + (2 * h) * AA + a) * NN;
    const float* r1 = scores + ((size_t)b * CC + (2 * h + 1) * AA + a) * NN;
    float v0[8], v1[8];
    float m0 = -1e30f, m1 = -1e30f;
#pragma unroll
    for (int k = 0; k < 8; ++k) {
        v0[k] = r0[tid + k * 256];
        v1[k] = r1[tid + k * 256];
        m0 = fmaxf(m0, v0[k]); m1 = fmaxf(m1, v1[k]);
    }
    __shared__ float redm[4][2];
    __shared__ float reds[4][2];
    int w = tid >> 6, lane = tid & 63;
#pragma unroll
    for (int off = 32; off; off >>= 1) {
        m0 = fmaxf(m0, __shfl_down(m0, off));
        m1 = fmaxf(m1, __shfl_down(m1, off));
    }
    if (lane == 0) { redm[w][0] = m0; redm[w][1] = m1; }
    __syncthreads();
    m0 = fmaxf(fmaxf(redm[0][0], redm[1][0]), fmaxf(redm[2][0], redm[3][0]));
    m1 = fmaxf(fmaxf(redm[0][1], redm[1][1]), fmaxf(redm[2][1], redm[3][1]));
    float s0 = 0.f, s1 = 0.f;
#pragma unroll
    for (int k = 0; k < 8; ++k) {
        v0[k] = expf(v0[k] - m0); s0 += v0[k];
        v1[k] = expf(v1[k] - m1); s1 += v1[k];
    }
#pragma unroll
    for (int off = 32; off; off >>= 1) {
        s0 += __shfl_down(s0, off);
        s1 += __shfl_down(s1, off);
    }
    if (lane == 0) { reds[w][0] = s0; reds[w][1] = s1; }
    __syncthreads();
    s0 = reds[0][0] + reds[1][0] + reds[2][0] + reds[3][0];
    s1 = reds[0][1] + reds[1][1] + reds[2][1] + reds[3][1];
    float lam = *lam_p;
    float inv0 = 1.f / s0;
    float inv1 = lam / s1;
    ushort* drow = diffb + ((size_t)b * 64 + a * 8 + h) * NN;   // r = a*8+h
#pragma unroll
    for (int k = 0; k < 8; ++k)
        drow[tid + k * 256] = f2bf(v0[k] * inv0 - v1[k] * inv1);
}

// ---------------- pass 3: aggp[s][b][r][j] = sum_{n in half s} diff[r][n] * x[n][j] (MFMA) ----------------
// block 256 thr = 4 waves: 64 r x 64 j; grid (16 b, 16 jt, 2 s); K-loop 1024 in steps of 32
__global__ __launch_bounds__(256) void k_agg(const float* __restrict__ x,
                                             const ushort* __restrict__ diffb,
                                             float* __restrict__ aggp) {
    __shared__ ushort xT[64 * 32];   // [j_local][n_local] bf16, 4 KB
    int b = blockIdx.x, jt = blockIdx.y, s = blockIdx.z;
    int j0 = jt * 64;
    int tid = threadIdx.x;
    int nl = tid & 31, jc = tid >> 5;       // staging: thread covers (n=nl, j=j0+jc*8..+7)
    int lane = tid & 63, w = tid >> 6;
    int l15 = lane & 15, kg = lane >> 4;
    int nbase = s * 1024;

    f32x4 acc[4] = {};
    const float* xb = x + (size_t)b * NN * DD;

    const float* src0 = xb + (size_t)(nbase + nl) * DD + j0 + jc * 8;
    float4 p0 = *(const float4*)(src0);
    float4 p1 = *(const float4*)(src0 + 4);

    const ushort* drow = diffb + (size_t)b * 64 * NN;

    for (int stp = 0; stp < 32; ++stp) {
        // transpose-convert current tile into LDS: xT[j][n]
        int jb = jc * 8;
        xT[(jb + 0) * 32 + nl] = f2bf(p0.x);
        xT[(jb + 1) * 32 + nl] = f2bf(p0.y);
        xT[(jb + 2) * 32 + nl] = f2bf(p0.z);
        xT[(jb + 3) * 32 + nl] = f2bf(p0.w);
        xT[(jb + 4) * 32 + nl] = f2bf(p1.x);
        xT[(jb + 5) * 32 + nl] = f2bf(p1.y);
        xT[(jb + 6) * 32 + nl] = f2bf(p1.z);
        xT[(jb + 7) * 32 + nl] = f2bf(p1.w);
        // prefetch next tile (in flight during compute)
        if (stp < 31) {
            const float* src = xb + (size_t)(nbase + (stp + 1) * 32 + nl) * DD + j0 + jc * 8;
            p0 = *(const float4*)(src);
            p1 = *(const float4*)(src + 4);
        }
        __syncthreads();
        int n0 = nbase + stp * 32;
        // A-frags from diffb (global, L2-hot): 4 r-tiles
        short8 af[4];
#pragma unroll
        for (int rt = 0; rt < 4; ++rt)
            af[rt] = __builtin_bit_cast(short8,
                *(const uint4*)(drow + (size_t)(rt * 16 + l15) * NN + n0 + kg * 8));
        // B-frag from LDS transposed tile: col j = w*16 + l15, k-slice kg*8
        short8 bv = __builtin_bit_cast(short8,
            *(const uint4*)(xT + (size_t)(w * 16 + l15) * 32 + kg * 8));
#pragma unroll
        for (int rt = 0; rt < 4; ++rt)
            acc[rt] = __builtin_amdgcn_mfma_f32_16x16x32_bf16(af[rt], bv, acc[rt], 0, 0, 0);
        __syncthreads();
    }
    // D: col=lane&15 -> j, row=(lane>>4)*4+reg -> r
    int jj = j0 + w * 16 + l15;
#pragma unroll
    for (int rt = 0; rt < 4; ++rt) {
#pragma unroll
        for (int reg = 0; reg < 4; ++reg) {
            int r = rt * 16 + kg * 4 + reg;
            aggp[(((size_t)s * BB + b) * 64 + r) * DD + jj] = acc[rt][reg];
        }
    }
}

// ---------------- pass 4a: yp[ks][row=b*8+a][p=h*128+e] ----------------
__global__ __launch_bounds__(256) void k_yp(const float* __restrict__ aggp,
                                            const float* __restrict__ Wv,
                                            float* __restrict__ yp) {
    __shared__ float Wvs[32][128];
    __shared__ float As[32][128];
    int h = blockIdx.x;     // 8
    int ks = blockIdx.y;    // 32
    int j0 = ks * 32;
    int tid = threadIdx.x;
    int tr = tid >> 4;
    int te = tid & 15;
#pragma unroll
    for (int t = 0; t < 4; ++t) {
        int f4 = tid + t * 256;
        int jj = f4 >> 5, e4 = (f4 & 31) * 4;
        *(float4*)(&Wvs[jj][e4]) = *(const float4*)(Wv + (size_t)(j0 + jj) * DD + h * TD + e4);
    }
#pragma unroll
    for (int t = 0; t < 4; ++t) {
        int f4 = tid + t * 256;
        int row = f4 >> 3;
        int j4 = (f4 & 7) * 4;
        int b_ = row >> 3, a_ = row & 7;
        size_t base = (((size_t)b_ * 64) + a_ * 8 + h) * DD + j0 + j4;
        float4 u = *(const float4*)(aggp + base);
        float4 v = *(const float4*)(aggp + (size_t)BB * 64 * DD + base);
        As[j4 + 0][row] = u.x + v.x; As[j4 + 1][row] = u.y + v.y;
        As[j4 + 2][row] = u.z + v.z; As[j4 + 3][row] = u.w + v.w;
    }
    __syncthreads();
    float acc[8][8] = {};
#pragma unroll
    for (int jj = 0; jj < 32; ++jj) {
        float4 a0 = *(const float4*)(&As[jj][tr * 8]);
        float4 a1 = *(const float4*)(&As[jj][tr * 8 + 4]);
        float4 w0 = *(const float4*)(&Wvs[jj][te * 8]);
        float4 w1 = *(const float4*)(&Wvs[jj][te * 8 + 4]);
        float av[8] = {a0.x, a0.y, a0.z, a0.w, a1.x, a1.y, a1.z, a1.w};
        float wv[8] = {w0.x, w0.y, w0.z, w0.w, w1.x, w1.y, w1.z, w1.w};
#pragma unroll
        for (int i = 0; i < 8; ++i)
#pragma unroll
            for (int k = 0; k < 8; ++k)
                acc[i][k] = fmaf(av[i], wv[k], acc[i][k]);
    }
#pragma unroll
    for (int i = 0; i < 8; ++i) {
        float4 o0 = {acc[i][0], acc[i][1], acc[i][2], acc[i][3]};
        float4 o1 = {acc[i][4], acc[i][5], acc[i][6], acc[i][7]};
        float* dst = yp + ((size_t)ks * 128 + tr * 8 + i) * DD + h * TD + te * 8;
        *(float4*)dst = o0;
        *(float4*)(dst + 4) = o1;
    }
}

// ---------------- pass 4b: reduce partials, RMSNorm, dot with wo_head ----------------
__global__ __launch_bounds__(256) void k_logits(const float* __restrict__ yp,
                                                const float* __restrict__ rms_w,
                                                const float* __restrict__ woh,
                                                float* __restrict__ logits) {
    int row = blockIdx.x;   // 128 = b*8+a
    int tid = threadIdx.x;
    __shared__ float hss[8];
    __shared__ float red[4];
    if (tid < 8) hss[tid] = 0.f;
    __syncthreads();
    float y[4];
#pragma unroll
    for (int k = 0; k < 4; ++k) {
        int p = tid + k * 256;
        float acc = 0.f;
#pragma unroll 8
        for (int ks = 0; ks < 32; ++ks)
            acc += yp[((size_t)ks * 128 + row) * DD + p];
        y[k] = acc;
        atomicAdd(&hss[p >> 7], acc * acc);
    }
    __syncthreads();
    float val = 0.f;
#pragma unroll
    for (int k = 0; k < 4; ++k) {
        int p = tid + k * 256;
        int h = p >> 7, e = p & 127;
        float rs = rsqrtf(hss[h] * (1.f / 128.f) + EPS_);
        val += y[k] * rs * rms_w[e] * (1.f - LAMBDA_INIT) * woh[p];
    }
#pragma unroll
    for (int off = 32; off; off >>= 1) val += __shfl_down(val, off);
    int w = tid >> 6, lane = tid & 63;
    if (lane == 0) red[w] = val;
    __syncthreads();
    if (tid == 0) logits[row] = red[0] + red[1] + red[2] + red[3];
}

extern "C" void kernel_launch(void* const* d_in, const int* in_sizes, int n_in,
                              void* d_out, int out_size, void* d_ws, size_t ws_size,
                              hipStream_t stream) {
    (void)in_sizes; (void)n_in; (void)out_size; (void)ws_size;
    const float* x       = (const float*)d_in[0];
    const float* atlas_q = (const float*)d_in[1];
    const float* Wq      = (const float*)d_in[2];
    const float* Wk      = (const float*)d_in[3];
    const float* Wv      = (const float*)d_in[4];
    const float* Wo      = (const float*)d_in[5];
    const float* rms_w   = (const float*)d_in[6];
    const float* Whead   = (const float*)d_in[7];
    const float* lq1     = (const float*)d_in[8];
    const float* lk1     = (const float*)d_in[9];
    const float* lq2     = (const float*)d_in[10];
    const float* lk2     = (const float*)d_in[11];
    float* out = (float*)d_out;
    float* ws  = (float*)d_ws;

    float*  qproj = ws + OFF_QPROJ;
    ushort* M2    = (ushort*)(ws + OFF_M2);
    float*  lam   = ws + OFF_LAM;
    float*  woh   = ws + OFF_WOH;
    float*  scores= ws + OFF_SC;
    ushort* diffb = (ushort*)(ws + OFF_DIFFB);
    float*  aggp  = ws + OFF_AGG;
    float*  yp    = ws + OFF_SC;   // reuse scores region (dead after k_softdiff)

    hipLaunchKernelGGL(k_qproj,    dim3(8, 4),      dim3(256), 0, stream, atlas_q, Wq, qproj);
    hipLaunchKernelGGL(k_lam,      dim3(1),         dim3(64),  0, stream, lq1, lk1, lq2, lk2, lam);
    hipLaunchKernelGGL(k_wohead,   dim3(4),         dim3(256), 0, stream, Wo, Whead, woh);
    hipLaunchKernelGGL(k_m2,       dim3(128),       dim3(256), 0, stream, qproj, Wk, M2);
    hipLaunchKernelGGL(k_scores,   dim3(16, 32),    dim3(256), 0, stream, x, M2, scores);
    hipLaunchKernelGGL(k_softdiff, dim3(1024),      dim3(256), 0, stream, scores, lam, diffb);
    hipLaunchKernelGGL(k_agg,      dim3(16, 16, 2), dim3(256), 0, stream, x, diffb, aggp);
    hipLaunchKernelGGL(k_yp,       dim3(8, 32),     dim3(256), 0, stream, aggp, Wv, yp);
    hipLaunchKernelGGL(k_logits,   dim3(128),       dim3(256), 0, stream, yp, rms_w, woh, out);
}

// Round 4
// 380.760 us; speedup vs baseline: 1.3849x; 1.1902x over previous
//
#include <hip/hip_runtime.h>
#include <hip/hip_bf16.h>
#include <cstdint>

#define BB 16      // batch
#define NN 2048    // tokens
#define DD 1024    // model dim
#define HH 8       // heads
#define AA 8       // atlas tokens
#define CC 128     // 2H * A score channels
#define DH 64      // half-head dim d
#define TD 128     // 2d
#define LAMBDA_INIT 0.8f
#define EPS_ 1e-5f

typedef short short8 __attribute__((ext_vector_type(8)));
typedef float f32x4  __attribute__((ext_vector_type(4)));

static __device__ __forceinline__ ushort f2bf(float f) {
    uint32_t u = __float_as_uint(f);
    return (ushort)((u + 0x8000u) >> 16);
}

// Workspace layout (float offsets). Lifetimes:
//  OFF_SC: scores (k_scores..k_softdiff), then aggp (k_agg..k_yp)  [both 4194304]
//  OFF_DIFFB: diffb (k_softdiff..k_agg), then Y 131072 floats (k_yp..k_logits)
static constexpr size_t OFF_QPROJP = 0;                      // 8*8*1024 = 65536
static constexpr size_t OFF_M2     = 65536;                  // 131072 ushort = 65536 float slots
static constexpr size_t OFF_LAM    = 131072;                 // 64
static constexpr size_t OFF_WOH    = 131136;                 // 1024
static constexpr size_t OFF_SC     = 132160;                 // 4194304
static constexpr size_t OFF_DIFFB  = OFF_SC + 4194304;       // 1048576 float slots
// end = 5375040 floats = 21.5 MB

// ---------------- fused setup: qproj partials (blk 0..127), wohead (128..191), lam (192) ----------------
__global__ __launch_bounds__(256) void k_setup(const float* __restrict__ atlas_q,
                                               const float* __restrict__ Wq,
                                               const float* __restrict__ Wo,
                                               const float* __restrict__ Whead,
                                               const float* __restrict__ lq1,
                                               const float* __restrict__ lk1,
                                               const float* __restrict__ lq2,
                                               const float* __restrict__ lk2,
                                               float* __restrict__ qprojp,
                                               float* __restrict__ woh,
                                               float* __restrict__ lam) {
    int blk = blockIdx.x;
    int tid = threadIdx.x;
    if (blk < 128) {
        // qprojp[iq][a][j] = sum_{i in iq-slice} aq[a][i] * Wq[i][j]
        __shared__ float aqS[8][128];
        __shared__ float redS[4][8][64];
        int jt = blk >> 3, iq = blk & 7;
        if (tid < 128) {
#pragma unroll
            for (int a = 0; a < 8; ++a) aqS[a][tid] = atlas_q[a * DD + iq * 128 + tid];
        }
        __syncthreads();
        int jl = tid & 63, is = tid >> 6;
        float acc[8] = {};
        const float* wq = Wq + (size_t)(iq * 128 + is * 32) * DD + jt * 64 + jl;
#pragma unroll 8
        for (int ii = 0; ii < 32; ++ii) {
            float wv = wq[(size_t)ii * DD];
            int i = is * 32 + ii;
#pragma unroll
            for (int a = 0; a < 8; ++a) acc[a] = fmaf(aqS[a][i], wv, acc[a]);
        }
#pragma unroll
        for (int a = 0; a < 8; ++a) redS[is][a][jl] = acc[a];
        __syncthreads();
        if (tid < 64) {
#pragma unroll
            for (int a = 0; a < 8; ++a)
                qprojp[(size_t)iq * 8192 + a * 1024 + jt * 64 + tid] =
                    redS[0][a][tid] + redS[1][a][tid] + redS[2][a][tid] + redS[3][a][tid];
        }
    } else if (blk < 192) {
        // woh[i] = sum_j Wo[i][j]*Whead[j]; 16 rows/block, 16 lanes per row
        int i0 = (blk - 128) * 16;
        int il = tid >> 4, jt = tid & 15;
        const float* row = Wo + (size_t)(i0 + il) * DD;
        float acc = 0.f;
#pragma unroll 4
        for (int u = 0; u < 16; ++u) {
            float4 r  = *(const float4*)(row + u * 64 + jt * 4);
            float4 wv = *(const float4*)(Whead + u * 64 + jt * 4);
            acc += r.x * wv.x + r.y * wv.y + r.z * wv.z + r.w * wv.w;
        }
#pragma unroll
        for (int off = 8; off; off >>= 1) acc += __shfl_down(acc, off);
        if ((tid & 15) == 0) woh[i0 + il] = acc;
    } else {
        if (tid < 64) {
            float p1 = lq1[tid] * lk1[tid];
            float p2 = lq2[tid] * lk2[tid];
#pragma unroll
            for (int off = 32; off; off >>= 1) {
                p1 += __shfl_down(p1, off);
                p2 += __shfl_down(p2, off);
            }
            if (tid == 0) *lam = expf(p1) - expf(p2) + LAMBDA_INIT;
        }
    }
}

// ---------------- M2[c][j] (bf16) = 0.125 * sum_t qproj[a][h2*64+t] * Wk[j][h2*64+t] ----------------
// 512 blocks x 2 j-rows; per-row coalesced loads; 16-lane segment shfl-reduce.
__global__ __launch_bounds__(256) void k_m2(const float* __restrict__ qprojp,
                                            const float* __restrict__ Wk,
                                            ushort* __restrict__ M2) {
    __shared__ float qpS[8192];
    int jb = blockIdx.x;
    int tid = threadIdx.x;
#pragma unroll
    for (int e = 0; e < 32; ++e) {
        int idx = tid + e * 256;
        float s = 0.f;
#pragma unroll
        for (int iq = 0; iq < 8; ++iq) s += qprojp[(size_t)iq * 8192 + idx];
        qpS[idx] = s;
    }
    __syncthreads();
    int h2 = tid >> 4;   // thread's 4 i's = h2*64 + (tid&15)*4 ..+3
#pragma unroll
    for (int jr = 0; jr < 2; ++jr) {
        int j = jb * 2 + jr;
        float4 wv = *(const float4*)(Wk + (size_t)j * DD + tid * 4);
        float p[8];
#pragma unroll
        for (int a = 0; a < 8; ++a) {
            float4 q4 = *(const float4*)(&qpS[a * DD + tid * 4]);
            p[a] = q4.x * wv.x + q4.y * wv.y + q4.z * wv.z + q4.w * wv.w;
        }
#pragma unroll
        for (int off = 8; off; off >>= 1)
#pragma unroll
            for (int a = 0; a < 8; ++a) p[a] += __shfl_down(p[a], off);
        if ((tid & 15) == 0) {
#pragma unroll
            for (int a = 0; a < 8; ++a)
                M2[(size_t)(h2 * 8 + a) * DD + j] = f2bf(p[a] * 0.125f);
        }
    }
}

// ---------------- pass 1: scores[b][c][n] = X @ M2^T via MFMA, 2-deep x prefetch ----------------
// grid (16 b, 64 nt) = 1024 blocks; block 4 waves: wn = w>>1 (n-tile), wc = w&1 (c-half)
__global__ __launch_bounds__(256, 4) void k_scores(const float* __restrict__ x,
                                                   const ushort* __restrict__ M2,
                                                   float* __restrict__ scores) {
    int b = blockIdx.x, nt = blockIdx.y;
    int tid = threadIdx.x;
    int lane = tid & 63, w = tid >> 6;
    int wn = w >> 1, wc = w & 1;
    int l15 = lane & 15, kg = lane >> 4;
    int n = nt * 32 + wn * 16 + l15;
    const float* xr = x + ((size_t)b * NN + n) * DD + kg * 8;

    f32x4 acc[4] = {};
    float4 pa0 = *(const float4*)(xr);
    float4 pa1 = *(const float4*)(xr + 4);
    float4 pa2 = *(const float4*)(xr + 32);
    float4 pa3 = *(const float4*)(xr + 36);

    for (int j0 = 0; j0 < DD; j0 += 64) {
        float4 ca0 = pa0, ca1 = pa1, ca2 = pa2, ca3 = pa3;
        if (j0 < DD - 64) {
            pa0 = *(const float4*)(xr + j0 + 64);
            pa1 = *(const float4*)(xr + j0 + 68);
            pa2 = *(const float4*)(xr + j0 + 96);
            pa3 = *(const float4*)(xr + j0 + 100);
        }
        short8 av0, av1;
        av0[0] = (short)f2bf(ca0.x); av0[1] = (short)f2bf(ca0.y);
        av0[2] = (short)f2bf(ca0.z); av0[3] = (short)f2bf(ca0.w);
        av0[4] = (short)f2bf(ca1.x); av0[5] = (short)f2bf(ca1.y);
        av0[6] = (short)f2bf(ca1.z); av0[7] = (short)f2bf(ca1.w);
        av1[0] = (short)f2bf(ca2.x); av1[1] = (short)f2bf(ca2.y);
        av1[2] = (short)f2bf(ca2.z); av1[3] = (short)f2bf(ca2.w);
        av1[4] = (short)f2bf(ca3.x); av1[5] = (short)f2bf(ca3.y);
        av1[6] = (short)f2bf(ca3.z); av1[7] = (short)f2bf(ca3.w);
        const ushort* m2b = M2 + (size_t)(wc * 64) * DD + j0 + kg * 8;
#pragma unroll
        for (int ct = 0; ct < 4; ++ct) {
            uint4 b0 = *(const uint4*)(m2b + (size_t)(ct * 16 + l15) * DD);
            uint4 b1 = *(const uint4*)(m2b + (size_t)(ct * 16 + l15) * DD + 32);
            acc[ct] = __builtin_amdgcn_mfma_f32_16x16x32_bf16(
                av0, __builtin_bit_cast(short8, b0), acc[ct], 0, 0, 0);
            acc[ct] = __builtin_amdgcn_mfma_f32_16x16x32_bf16(
                av1, __builtin_bit_cast(short8, b1), acc[ct], 0, 0, 0);
        }
    }
    // D: col(l15)->c, row(kg*4+reg)->n
#pragma unroll
    for (int ct = 0; ct < 4; ++ct) {
        int c = wc * 64 + ct * 16 + l15;
        float4 o = {acc[ct][0], acc[ct][1], acc[ct][2], acc[ct][3]};
        *(float4*)(scores + ((size_t)b * CC + c) * NN + nt * 32 + wn * 16 + kg * 4) = o;
    }
}

// ---------------- pass 2: softmax + differential combine -> bf16 diffb[b][a*8+h][n] ----------------
__global__ __launch_bounds__(256) void k_softdiff(const float* __restrict__ scores,
                                                  const float* __restrict__ lam_p,
                                                  ushort* __restrict__ diffb) {
    int blk = blockIdx.x;   // b*64 + h*8 + a
    int b = blk >> 6, h = (blk >> 3) & 7, a = blk & 7;
    int tid = threadIdx.x;
    const float* r0 = scores + ((size_t)b * CC + (2 * h) * AA + a) * NN;
    const float* r1 = scores + ((size_t)b * CC + (2 * h + 1) * AA + a) * NN;
    float v0[8], v1[8];
    float m0 = -1e30f, m1 = -1e30f;
#pragma unroll
    for (int k = 0; k < 8; ++k) {
        v0[k] = r0[tid + k * 256];
        v1[k] = r1[tid + k * 256];
        m0 = fmaxf(m0, v0[k]); m1 = fmaxf(m1, v1[k]);
    }
    __shared__ float redm[4][2];
    __shared__ float reds[4][2];
    int w = tid >> 6, lane = tid & 63;
#pragma unroll
    for (int off = 32; off; off >>= 1) {
        m0 = fmaxf(m0, __shfl_down(m0, off));
        m1 = fmaxf(m1, __shfl_down(m1, off));
    }
    if (lane == 0) { redm[w][0] = m0; redm[w][1] = m1; }
    __syncthreads();
    m0 = fmaxf(fmaxf(redm[0][0], redm[1][0]), fmaxf(redm[2][0], redm[3][0]));
    m1 = fmaxf(fmaxf(redm[0][1], redm[1][1]), fmaxf(redm[2][1], redm[3][1]));
    float s0 = 0.f, s1 = 0.f;
#pragma unroll
    for (int k = 0; k < 8; ++k) {
        v0[k] = expf(v0[k] - m0); s0 += v0[k];
        v1[k] = expf(v1[k] - m1); s1 += v1[k];
    }
#pragma unroll
    for (int off = 32; off; off >>= 1) {
        s0 += __shfl_down(s0, off);
        s1 += __shfl_down(s1, off);
    }
    if (lane == 0) { reds[w][0] = s0; reds[w][1] = s1; }
    __syncthreads();
    s0 = reds[0][0] + reds[1][0] + reds[2][0] + reds[3][0];
    s1 = reds[0][1] + reds[1][1] + reds[2][1] + reds[3][1];
    float lam = *lam_p;
    float inv0 = 1.f / s0;
    float inv1 = lam / s1;
    ushort* drow = diffb + ((size_t)b * 64 + a * 8 + h) * NN;   // r = a*8+h
#pragma unroll
    for (int k = 0; k < 8; ++k)
        drow[tid + k * 256] = f2bf(v0[k] * inv0 - v1[k] * inv1);
}

// ---------------- pass 3: aggp[sk][b][r][j] = sum_{n in sk-quarter} diff[r][n]*x[n][j] ----------------
// grid (16 b, 16 jt, 4 sk) = 1024 blocks; K=512 per block; prefetch x-tile + A-frags
__global__ __launch_bounds__(256, 4) void k_agg(const float* __restrict__ x,
                                                const ushort* __restrict__ diffb,
                                                float* __restrict__ aggp) {
    __shared__ ushort xT[64 * 32];   // [j_local][n_local] bf16
    int b = blockIdx.x, jt = blockIdx.y, sk = blockIdx.z;
    int j0 = jt * 64;
    int tid = threadIdx.x;
    int nl = tid & 31, jc = tid >> 5;
    int lane = tid & 63, w = tid >> 6;
    int l15 = lane & 15, kg = lane >> 4;
    int nbase = sk * 512;

    f32x4 acc[4] = {};
    const float* xb = x + (size_t)b * NN * DD;
    const ushort* drow = diffb + (size_t)b * 64 * NN;

    const float* s0p = xb + (size_t)(nbase + nl) * DD + j0 + jc * 8;
    float4 p0 = *(const float4*)(s0p);
    float4 p1 = *(const float4*)(s0p + 4);
    uint4 an[4];
#pragma unroll
    for (int rt = 0; rt < 4; ++rt)
        an[rt] = *(const uint4*)(drow + (size_t)(rt * 16 + l15) * NN + nbase + kg * 8);

    for (int stp = 0; stp < 16; ++stp) {
        int jb = jc * 8;
        xT[(jb + 0) * 32 + nl] = f2bf(p0.x);
        xT[(jb + 1) * 32 + nl] = f2bf(p0.y);
        xT[(jb + 2) * 32 + nl] = f2bf(p0.z);
        xT[(jb + 3) * 32 + nl] = f2bf(p0.w);
        xT[(jb + 4) * 32 + nl] = f2bf(p1.x);
        xT[(jb + 5) * 32 + nl] = f2bf(p1.y);
        xT[(jb + 6) * 32 + nl] = f2bf(p1.z);
        xT[(jb + 7) * 32 + nl] = f2bf(p1.w);
        uint4 ac0 = an[0], ac1 = an[1], ac2 = an[2], ac3 = an[3];
        if (stp < 15) {
            int n1 = nbase + (stp + 1) * 32;
            const float* sp = xb + (size_t)(n1 + nl) * DD + j0 + jc * 8;
            p0 = *(const float4*)(sp);
            p1 = *(const float4*)(sp + 4);
#pragma unroll
            for (int rt = 0; rt < 4; ++rt)
                an[rt] = *(const uint4*)(drow + (size_t)(rt * 16 + l15) * NN + n1 + kg * 8);
        }
        __syncthreads();
        short8 bv = __builtin_bit_cast(short8,
            *(const uint4*)(xT + (size_t)(w * 16 + l15) * 32 + kg * 8));
        acc[0] = __builtin_amdgcn_mfma_f32_16x16x32_bf16(__builtin_bit_cast(short8, ac0), bv, acc[0], 0, 0, 0);
        acc[1] = __builtin_amdgcn_mfma_f32_16x16x32_bf16(__builtin_bit_cast(short8, ac1), bv, acc[1], 0, 0, 0);
        acc[2] = __builtin_amdgcn_mfma_f32_16x16x32_bf16(__builtin_bit_cast(short8, ac2), bv, acc[2], 0, 0, 0);
        acc[3] = __builtin_amdgcn_mfma_f32_16x16x32_bf16(__builtin_bit_cast(short8, ac3), bv, acc[3], 0, 0, 0);
        __syncthreads();
    }
    int jj = j0 + w * 16 + l15;
#pragma unroll
    for (int rt = 0; rt < 4; ++rt) {
#pragma unroll
        for (int reg = 0; reg < 4; ++reg) {
            int r = rt * 16 + kg * 4 + reg;
            aggp[(((size_t)sk * BB + b) * 64 + r) * DD + jj] = acc[rt][reg];
        }
    }
}

// ---------------- pass 4a: Y[row][h*128+e] = sum_j agg[row,h][j] * Wv[j][h*128+e], full K ----------------
// grid (8 h, 16 rt): block = 8 rows x 128 e
__global__ __launch_bounds__(256) void k_yp(const float* __restrict__ aggp,
                                            const float* __restrict__ Wv,
                                            float* __restrict__ Y) {
    __shared__ float As[8][32];
    __shared__ float Ws[32][128];
    int h = blockIdx.x, rt = blockIdx.y;
    int tid = threadIdx.x;
    int rl = tid >> 5, te = tid & 31;
    int row0 = rt * 8;
    float a0 = 0.f, a1 = 0.f, a2 = 0.f, a3 = 0.f;
    for (int j0 = 0; j0 < DD; j0 += 32) {
        {
            int r = row0 + rl;
            int b_ = r >> 3, a_ = r & 7;
            size_t base = (((size_t)b_ * 64) + a_ * 8 + h) * DD + j0 + te;
            const size_t skS = (size_t)BB * 64 * DD;
            As[rl][te] = aggp[base] + aggp[base + skS] + aggp[base + 2 * skS] + aggp[base + 3 * skS];
        }
#pragma unroll
        for (int t = 0; t < 4; ++t) {
            int f4 = tid + t * 256;
            int jj = f4 >> 5, e4 = (f4 & 31) * 4;
            *(float4*)(&Ws[jj][e4]) = *(const float4*)(Wv + (size_t)(j0 + jj) * DD + h * TD + e4);
        }
        __syncthreads();
#pragma unroll
        for (int jj = 0; jj < 32; ++jj) {
            float av = As[rl][jj];
            float4 w4 = *(const float4*)(&Ws[jj][te * 4]);
            a0 = fmaf(av, w4.x, a0);
            a1 = fmaf(av, w4.y, a1);
            a2 = fmaf(av, w4.z, a2);
            a3 = fmaf(av, w4.w, a3);
        }
        __syncthreads();
    }
    float4 o = {a0, a1, a2, a3};
    *(float4*)(Y + (size_t)(row0 + rl) * DD + h * TD + te * 4) = o;
}

// ---------------- pass 4b: RMSNorm + dot with wo_head ----------------
__global__ __launch_bounds__(256) void k_logits(const float* __restrict__ Y,
                                                const float* __restrict__ rms_w,
                                                const float* __restrict__ woh,
                                                float* __restrict__ logits) {
    int row = blockIdx.x;   // 128 = b*8+a
    int tid = threadIdx.x;
    int w = tid >> 6, lane = tid & 63;
    __shared__ float hss[8];
    __shared__ float red[4];
    float y[4];
    if (tid < 8) hss[tid] = 0.f;
    __syncthreads();
#pragma unroll
    for (int k = 0; k < 4; ++k) {
        int p = k * 256 + tid;
        y[k] = Y[(size_t)row * DD + p];
        float s = y[k] * y[k];
#pragma unroll
        for (int off = 32; off; off >>= 1) s += __shfl_down(s, off);
        if (lane == 0) atomicAdd(&hss[(k * 256 + w * 64) >> 7], s);  // h uniform per (k,w)
    }
    __syncthreads();
    float val = 0.f;
#pragma unroll
    for (int k = 0; k < 4; ++k) {
        int p = k * 256 + tid;
        int hh = p >> 7, e = p & 127;
        float rs = rsqrtf(hss[hh] * (1.f / 128.f) + EPS_);
        val += y[k] * rs * rms_w[e] * (1.f - LAMBDA_INIT) * woh[p];
    }
#pragma unroll
    for (int off = 32; off; off >>= 1) val += __shfl_down(val, off);
    if (lane == 0) red[w] = val;
    __syncthreads();
    if (tid == 0) logits[row] = red[0] + red[1] + red[2] + red[3];
}

extern "C" void kernel_launch(void* const* d_in, const int* in_sizes, int n_in,
                              void* d_out, int out_size, void* d_ws, size_t ws_size,
                              hipStream_t stream) {
    (void)in_sizes; (void)n_in; (void)out_size; (void)ws_size;
    const float* x       = (const float*)d_in[0];
    const float* atlas_q = (const float*)d_in[1];
    const float* Wq      = (const float*)d_in[2];
    const float* Wk      = (const float*)d_in[3];
    const float* Wv      = (const float*)d_in[4];
    const float* Wo      = (const float*)d_in[5];
    const float* rms_w   = (const float*)d_in[6];
    const float* Whead   = (const float*)d_in[7];
    const float* lq1     = (const float*)d_in[8];
    const float* lk1     = (const float*)d_in[9];
    const float* lq2     = (const float*)d_in[10];
    const float* lk2     = (const float*)d_in[11];
    float* out = (float*)d_out;
    float* ws  = (float*)d_ws;

    float*  qprojp = ws + OFF_QPROJP;
    ushort* M2     = (ushort*)(ws + OFF_M2);
    float*  lam    = ws + OFF_LAM;
    float*  woh    = ws + OFF_WOH;
    float*  scores = ws + OFF_SC;
    float*  aggp   = ws + OFF_SC;      // reuse: scores dead after k_softdiff
    ushort* diffb  = (ushort*)(ws + OFF_DIFFB);
    float*  Y      = ws + OFF_DIFFB;   // reuse: diffb dead after k_agg

    hipLaunchKernelGGL(k_setup,    dim3(193),       dim3(256), 0, stream,
                       atlas_q, Wq, Wo, Whead, lq1, lk1, lq2, lk2, qprojp, woh, lam);
    hipLaunchKernelGGL(k_m2,       dim3(512),       dim3(256), 0, stream, qprojp, Wk, M2);
    hipLaunchKernelGGL(k_scores,   dim3(16, 64),    dim3(256), 0, stream, x, M2, scores);
    hipLaunchKernelGGL(k_softdiff, dim3(1024),      dim3(256), 0, stream, scores, lam, diffb);
    hipLaunchKernelGGL(k_agg,      dim3(16, 16, 4), dim3(256), 0, stream, x, diffb, aggp);
    hipLaunchKernelGGL(k_yp,       dim3(8, 16),     dim3(256), 0, stream, aggp, Wv, Y);
    hipLaunchKernelGGL(k_logits,   dim3(128),       dim3(256), 0, stream, Y, rms_w, woh, out);
}

// Round 5
// 308.722 us; speedup vs baseline: 1.7080x; 1.2333x over previous
//
#include <hip/hip_runtime.h>
#include <hip/hip_bf16.h>
#include <cstdint>

#define BB 16      // batch
#define NN 2048    // tokens
#define DD 1024    // model dim
#define HH 8       // heads
#define AA 8       // atlas tokens
#define CC 128     // 2H * A score channels
#define DH 64      // half-head dim d
#define TD 128     // 2d
#define LAMBDA_INIT 0.8f
#define EPS_ 1e-5f

typedef short short8 __attribute__((ext_vector_type(8)));
typedef float f32x4  __attribute__((ext_vector_type(4)));

static __device__ __forceinline__ ushort f2bf(float f) {
    uint32_t u = __float_as_uint(f);
    return (ushort)((u + 0x8000u) >> 16);
}
static __device__ __forceinline__ uint pack2(float a, float b) {
    return (uint)f2bf(a) | ((uint)f2bf(b) << 16);
}

// Workspace layout (float offsets). Lifetimes:
//  OFF_SC: scores (k_scores..k_softdiff), then aggp[4][16][64][1024] (k_agg..k_yp)
//  OFF_DIFFB: diffb bf16 (k_softdiff..k_agg), then ypp[4][128][1024] (k_yp..k_logits)
static constexpr size_t OFF_QPROJP = 0;                      // 65536
static constexpr size_t OFF_M2     = 65536;                  // 131072 ushort = 65536 float slots
static constexpr size_t OFF_LAM    = 131072;                 // 64
static constexpr size_t OFF_WOH    = 131136;                 // 1024
static constexpr size_t OFF_SC     = 132160;                 // 4194304
static constexpr size_t OFF_DIFFB  = OFF_SC + 4194304;       // 1048576
// end = 5375040 floats = 21.5 MB

// ---------------- fused setup: qproj partials (blk 0..127), wohead (128..191), lam (192) ----------------
__global__ __launch_bounds__(256) void k_setup(const float* __restrict__ atlas_q,
                                               const float* __restrict__ Wq,
                                               const float* __restrict__ Wo,
                                               const float* __restrict__ Whead,
                                               const float* __restrict__ lq1,
                                               const float* __restrict__ lk1,
                                               const float* __restrict__ lq2,
                                               const float* __restrict__ lk2,
                                               float* __restrict__ qprojp,
                                               float* __restrict__ woh,
                                               float* __restrict__ lam) {
    int blk = blockIdx.x;
    int tid = threadIdx.x;
    if (blk < 128) {
        __shared__ float aqS[8][128];
        __shared__ float redS[4][8][64];
        int jt = blk >> 3, iq = blk & 7;
        if (tid < 128) {
#pragma unroll
            for (int a = 0; a < 8; ++a) aqS[a][tid] = atlas_q[a * DD + iq * 128 + tid];
        }
        __syncthreads();
        int jl = tid & 63, is = tid >> 6;
        float acc[8] = {};
        const float* wq = Wq + (size_t)(iq * 128 + is * 32) * DD + jt * 64 + jl;
#pragma unroll 8
        for (int ii = 0; ii < 32; ++ii) {
            float wv = wq[(size_t)ii * DD];
            int i = is * 32 + ii;
#pragma unroll
            for (int a = 0; a < 8; ++a) acc[a] = fmaf(aqS[a][i], wv, acc[a]);
        }
#pragma unroll
        for (int a = 0; a < 8; ++a) redS[is][a][jl] = acc[a];
        __syncthreads();
        if (tid < 64) {
#pragma unroll
            for (int a = 0; a < 8; ++a)
                qprojp[(size_t)iq * 8192 + a * 1024 + jt * 64 + tid] =
                    redS[0][a][tid] + redS[1][a][tid] + redS[2][a][tid] + redS[3][a][tid];
        }
    } else if (blk < 192) {
        int i0 = (blk - 128) * 16;
        int il = tid >> 4, jt = tid & 15;
        const float* row = Wo + (size_t)(i0 + il) * DD;
        float acc = 0.f;
#pragma unroll 4
        for (int u = 0; u < 16; ++u) {
            float4 r  = *(const float4*)(row + u * 64 + jt * 4);
            float4 wv = *(const float4*)(Whead + u * 64 + jt * 4);
            acc += r.x * wv.x + r.y * wv.y + r.z * wv.z + r.w * wv.w;
        }
#pragma unroll
        for (int off = 8; off; off >>= 1) acc += __shfl_down(acc, off);
        if ((tid & 15) == 0) woh[i0 + il] = acc;
    } else {
        if (tid < 64) {
            float p1 = lq1[tid] * lk1[tid];
            float p2 = lq2[tid] * lk2[tid];
#pragma unroll
            for (int off = 32; off; off >>= 1) {
                p1 += __shfl_down(p1, off);
                p2 += __shfl_down(p2, off);
            }
            if (tid == 0) *lam = expf(p1) - expf(p2) + LAMBDA_INIT;
        }
    }
}

// ---------------- M2[c][j] (bf16) = 0.125 * sum_t qproj[a][h2*64+t] * Wk[j][h2*64+t] ----------------
__global__ __launch_bounds__(256) void k_m2(const float* __restrict__ qprojp,
                                            const float* __restrict__ Wk,
                                            ushort* __restrict__ M2) {
    __shared__ float qpS[8192];
    int jb = blockIdx.x;
    int tid = threadIdx.x;
#pragma unroll
    for (int e = 0; e < 32; ++e) {
        int idx = tid + e * 256;
        float s = 0.f;
#pragma unroll
        for (int iq = 0; iq < 8; ++iq) s += qprojp[(size_t)iq * 8192 + idx];
        qpS[idx] = s;
    }
    __syncthreads();
    int h2 = tid >> 4;
#pragma unroll
    for (int jr = 0; jr < 2; ++jr) {
        int j = jb * 2 + jr;
        float4 wv = *(const float4*)(Wk + (size_t)j * DD + tid * 4);
        float p[8];
#pragma unroll
        for (int a = 0; a < 8; ++a) {
            float4 q4 = *(const float4*)(&qpS[a * DD + tid * 4]);
            p[a] = q4.x * wv.x + q4.y * wv.y + q4.z * wv.z + q4.w * wv.w;
        }
#pragma unroll
        for (int off = 8; off; off >>= 1)
#pragma unroll
            for (int a = 0; a < 8; ++a) p[a] += __shfl_down(p[a], off);
        if ((tid & 15) == 0) {
#pragma unroll
            for (int a = 0; a < 8; ++a)
                M2[(size_t)(h2 * 8 + a) * DD + j] = f2bf(p[a] * 0.125f);
        }
    }
}

// ---------------- pass 1: scores = X @ M2^T, LDS-staged double-buffered MFMA GEMM ----------------
// grid (16 b, 32 nt); block 256 = 4 waves; tile 64n x 128c; K-chunks of 64 j.
// Wave w owns c in [w*32, w*32+32), all 64 n.
__global__ __launch_bounds__(256) void k_scores(const float* __restrict__ x,
                                                const ushort* __restrict__ M2,
                                                float* __restrict__ scores) {
    __shared__ ushort xs[2][64][72];    // [n][j] bf16, pad 72 (144B rows, 16B-aligned)
    __shared__ ushort ms[2][128][72];   // [c][j] bf16
    int b = blockIdx.x, nt = blockIdx.y;
    int tid = threadIdx.x;
    int lane = tid & 63, w = tid >> 6;
    int l15 = lane & 15, kg = lane >> 4;
    int xr4 = tid >> 4, xq = tid & 15;   // x staging: 16 rows/pass, 4 fp32/thread
    int mr  = tid >> 3, mq = tid & 7;    // M2 staging: 32 rows/pass, 8 bf16/thread
    const float* xbase = x + ((size_t)b * NN + nt * 64) * DD;

    f32x4 acc[4][2] = {};   // [nt2][ct2]

    float4 RXa[4], RXb[4];
    uint4  RMa[4], RMb[4];

    auto LOAD = [&](float4 (&RX)[4], uint4 (&RM)[4], int j0) {
#pragma unroll
        for (int p = 0; p < 4; ++p)
            RX[p] = *(const float4*)(xbase + (size_t)(p * 16 + xr4) * DD + j0 + xq * 4);
#pragma unroll
        for (int p = 0; p < 4; ++p)
            RM[p] = *(const uint4*)(M2 + (size_t)(p * 32 + mr) * DD + j0 + mq * 8);
    };
    auto WRITE = [&](int buf, float4 (&RX)[4], uint4 (&RM)[4]) {
#pragma unroll
        for (int p = 0; p < 4; ++p) {
            uint* d = (uint*)&xs[buf][p * 16 + xr4][xq * 4];
            d[0] = pack2(RX[p].x, RX[p].y);
            d[1] = pack2(RX[p].z, RX[p].w);
        }
#pragma unroll
        for (int p = 0; p < 4; ++p) {
            uint* d = (uint*)&ms[buf][p * 32 + mr][mq * 8];
            d[0] = RM[p].x; d[1] = RM[p].y; d[2] = RM[p].z; d[3] = RM[p].w;
        }
    };
    auto COMPUTE = [&](int buf) {
#pragma unroll
        for (int ks = 0; ks < 2; ++ks) {
            short8 av[4];
#pragma unroll
            for (int nt2 = 0; nt2 < 4; ++nt2)
                av[nt2] = *(const short8*)&xs[buf][nt2 * 16 + l15][ks * 32 + kg * 8];
#pragma unroll
            for (int ct2 = 0; ct2 < 2; ++ct2) {
                short8 bv = *(const short8*)&ms[buf][w * 32 + ct2 * 16 + l15][ks * 32 + kg * 8];
#pragma unroll
                for (int nt2 = 0; nt2 < 4; ++nt2)
                    acc[nt2][ct2] = __builtin_amdgcn_mfma_f32_16x16x32_bf16(av[nt2], bv, acc[nt2][ct2], 0, 0, 0);
            }
        }
    };

    LOAD(RXa, RMa, 0);
#pragma unroll 1
    for (int cc = 0; cc < 8; ++cc) {
        int c0 = cc * 2;
        LOAD(RXb, RMb, (c0 + 1) * 64);
        WRITE(0, RXa, RMa);
        __syncthreads();
        COMPUTE(0);
        if (c0 + 2 < 16) LOAD(RXa, RMa, (c0 + 2) * 64);
        WRITE(1, RXb, RMb);
        __syncthreads();
        COMPUTE(1);
    }
    // D: col=l15 -> c, row=kg*4+reg -> n (4 consecutive n per lane)
#pragma unroll
    for (int nt2 = 0; nt2 < 4; ++nt2)
#pragma unroll
        for (int ct2 = 0; ct2 < 2; ++ct2) {
            int c = w * 32 + ct2 * 16 + l15;
            float4 o = {acc[nt2][ct2][0], acc[nt2][ct2][1], acc[nt2][ct2][2], acc[nt2][ct2][3]};
            *(float4*)(scores + ((size_t)b * CC + c) * NN + nt * 64 + nt2 * 16 + kg * 4) = o;
        }
}

// ---------------- pass 2: softmax + differential combine -> bf16 diffb[b][a*8+h][n] ----------------
__global__ __launch_bounds__(256) void k_softdiff(const float* __restrict__ scores,
                                                  const float* __restrict__ lam_p,
                                                  ushort* __restrict__ diffb) {
    int blk = blockIdx.x;
    int b = blk >> 6, h = (blk >> 3) & 7, a = blk & 7;
    int tid = threadIdx.x;
    const float* r0 = scores + ((size_t)b * CC + (2 * h) * AA + a) * NN;
    const float* r1 = scores + ((size_t)b * CC + (2 * h + 1) * AA + a) * NN;
    float v0[8], v1[8];
    float m0 = -1e30f, m1 = -1e30f;
#pragma unroll
    for (int k = 0; k < 8; ++k) {
        v0[k] = r0[tid + k * 256];
        v1[k] = r1[tid + k * 256];
        m0 = fmaxf(m0, v0[k]); m1 = fmaxf(m1, v1[k]);
    }
    __shared__ float redm[4][2];
    __shared__ float reds[4][2];
    int w = tid >> 6, lane = tid & 63;
#pragma unroll
    for (int off = 32; off; off >>= 1) {
        m0 = fmaxf(m0, __shfl_down(m0, off));
        m1 = fmaxf(m1, __shfl_down(m1, off));
    }
    if (lane == 0) { redm[w][0] = m0; redm[w][1] = m1; }
    __syncthreads();
    m0 = fmaxf(fmaxf(redm[0][0], redm[1][0]), fmaxf(redm[2][0], redm[3][0]));
    m1 = fmaxf(fmaxf(redm[0][1], redm[1][1]), fmaxf(redm[2][1], redm[3][1]));
    float s0 = 0.f, s1 = 0.f;
#pragma unroll
    for (int k = 0; k < 8; ++k) {
        v0[k] = expf(v0[k] - m0); s0 += v0[k];
        v1[k] = expf(v1[k] - m1); s1 += v1[k];
    }
#pragma unroll
    for (int off = 32; off; off >>= 1) {
        s0 += __shfl_down(s0, off);
        s1 += __shfl_down(s1, off);
    }
    if (lane == 0) { reds[w][0] = s0; reds[w][1] = s1; }
    __syncthreads();
    s0 = reds[0][0] + reds[1][0] + reds[2][0] + reds[3][0];
    s1 = reds[0][1] + reds[1][1] + reds[2][1] + reds[3][1];
    float lam = *lam_p;
    float inv0 = 1.f / s0;
    float inv1 = lam / s1;
    ushort* drow = diffb + ((size_t)b * 64 + a * 8 + h) * NN;
#pragma unroll
    for (int k = 0; k < 8; ++k)
        drow[tid + k * 256] = f2bf(v0[k] * inv0 - v1[k] * inv1);
}

// ---------------- pass 3: aggp[sk][b][r][j] = sum_n diff[r][n]*x[n][j], LDS-staged xT ----------------
// grid (16 b, 16 jt, 4 sk); block 4 waves; tile 64r x 64j; n-chunks of 64 within sk's 512.
__global__ __launch_bounds__(256, 3) void k_agg(const float* __restrict__ x,
                                                const ushort* __restrict__ diffb,
                                                float* __restrict__ aggp) {
    __shared__ ushort xT[2][64][72];   // [j_local][n_local] bf16
    int b = blockIdx.x, jt = blockIdx.y, sk = blockIdx.z;
    int j0 = jt * 64, nbase = sk * 512;
    int tid = threadIdx.x;
    int nr = tid >> 3, jq = tid & 7;     // staging: 32 n-rows/pass, 8 fp32 j/thread
    int lane = tid & 63, w = tid >> 6;
    int l15 = lane & 15, kg = lane >> 4;
    const float* xb = x + (size_t)b * NN * DD;
    const ushort* drow = diffb + (size_t)b * 64 * NN;

    f32x4 acc[4] = {};

    float4 PXa[2][2], PXb[2][2];
    uint4  ANa[4][2], ANb[4][2];

    auto LOADX = [&](float4 (&P)[2][2], int c) {
#pragma unroll
        for (int p = 0; p < 2; ++p) {
            const float* s = xb + (size_t)(nbase + c * 64 + p * 32 + nr) * DD + j0 + jq * 8;
            P[p][0] = *(const float4*)(s);
            P[p][1] = *(const float4*)(s + 4);
        }
    };
    auto LOADA = [&](uint4 (&A)[4][2], int c) {
#pragma unroll
        for (int rt = 0; rt < 4; ++rt)
#pragma unroll
            for (int ks = 0; ks < 2; ++ks)
                A[rt][ks] = *(const uint4*)(drow + (size_t)(rt * 16 + l15) * NN
                                            + nbase + c * 64 + ks * 32 + kg * 8);
    };
    auto WRITE = [&](int buf, float4 (&P)[2][2]) {
#pragma unroll
        for (int p = 0; p < 2; ++p) {
            int n = p * 32 + nr;
            xT[buf][jq * 8 + 0][n] = f2bf(P[p][0].x);
            xT[buf][jq * 8 + 1][n] = f2bf(P[p][0].y);
            xT[buf][jq * 8 + 2][n] = f2bf(P[p][0].z);
            xT[buf][jq * 8 + 3][n] = f2bf(P[p][0].w);
            xT[buf][jq * 8 + 4][n] = f2bf(P[p][1].x);
            xT[buf][jq * 8 + 5][n] = f2bf(P[p][1].y);
            xT[buf][jq * 8 + 6][n] = f2bf(P[p][1].z);
            xT[buf][jq * 8 + 7][n] = f2bf(P[p][1].w);
        }
    };
    auto COMPUTE = [&](int buf, uint4 (&A)[4][2]) {
#pragma unroll
        for (int ks = 0; ks < 2; ++ks) {
            short8 bv = *(const short8*)&xT[buf][w * 16 + l15][ks * 32 + kg * 8];
#pragma unroll
            for (int rt = 0; rt < 4; ++rt)
                acc[rt] = __builtin_amdgcn_mfma_f32_16x16x32_bf16(
                    __builtin_bit_cast(short8, A[rt][ks]), bv, acc[rt], 0, 0, 0);
        }
    };

    LOADX(PXa, 0); LOADA(ANa, 0);
#pragma unroll 1
    for (int cc = 0; cc < 4; ++cc) {
        int c0 = cc * 2;
        LOADX(PXb, c0 + 1); LOADA(ANb, c0 + 1);
        WRITE(0, PXa);
        __syncthreads();
        COMPUTE(0, ANa);
        if (c0 + 2 < 8) { LOADX(PXa, c0 + 2); LOADA(ANa, c0 + 2); }
        WRITE(1, PXb);
        __syncthreads();
        COMPUTE(1, ANb);
    }
    int jj = j0 + w * 16 + l15;
#pragma unroll
    for (int rt = 0; rt < 4; ++rt)
#pragma unroll
        for (int reg = 0; reg < 4; ++reg) {
            int r = rt * 16 + kg * 4 + reg;
            aggp[(((size_t)sk * BB + b) * 64 + r) * DD + jj] = acc[rt][reg];
        }
}

// ---------------- pass 4a: ypp[jp][row][h*128+e] partial over j-quarter jp ----------------
// grid (8 h, 16 rt, 4 jp): block = 8 rows x 128 e over 256 j
__global__ __launch_bounds__(256) void k_yp(const float* __restrict__ aggp,
                                            const float* __restrict__ Wv,
                                            float* __restrict__ ypp) {
    __shared__ float As[8][32];
    __shared__ float Ws[32][128];
    int h = blockIdx.x, rt = blockIdx.y, jp = blockIdx.z;
    int tid = threadIdx.x;
    int rl = tid >> 5, te = tid & 31;
    int row0 = rt * 8;
    float a0 = 0.f, a1 = 0.f, a2 = 0.f, a3 = 0.f;
    for (int j0 = jp * 256; j0 < jp * 256 + 256; j0 += 32) {
        {
            int r = row0 + rl;
            int b_ = r >> 3, a_ = r & 7;
            size_t base = (((size_t)b_ * 64) + a_ * 8 + h) * DD + j0 + te;
            const size_t skS = (size_t)BB * 64 * DD;
            As[rl][te] = aggp[base] + aggp[base + skS] + aggp[base + 2 * skS] + aggp[base + 3 * skS];
        }
#pragma unroll
        for (int t = 0; t < 4; ++t) {
            int f4 = tid + t * 256;
            int jj = f4 >> 5, e4 = (f4 & 31) * 4;
            *(float4*)(&Ws[jj][e4]) = *(const float4*)(Wv + (size_t)(j0 + jj) * DD + h * TD + e4);
        }
        __syncthreads();
#pragma unroll
        for (int jj = 0; jj < 32; ++jj) {
            float av = As[rl][jj];
            float4 w4 = *(const float4*)(&Ws[jj][te * 4]);
            a0 = fmaf(av, w4.x, a0);
            a1 = fmaf(av, w4.y, a1);
            a2 = fmaf(av, w4.z, a2);
            a3 = fmaf(av, w4.w, a3);
        }
        __syncthreads();
    }
    float4 o = {a0, a1, a2, a3};
    *(float4*)(ypp + ((size_t)jp * 128 + row0 + rl) * DD + h * TD + te * 4) = o;
}

// ---------------- pass 4b: sum partials, RMSNorm, dot with wo_head ----------------
__global__ __launch_bounds__(256) void k_logits(const float* __restrict__ ypp,
                                                const float* __restrict__ rms_w,
                                                const float* __restrict__ woh,
                                                float* __restrict__ logits) {
    int row = blockIdx.x;   // 128 = b*8+a
    int tid = threadIdx.x;
    int w = tid >> 6, lane = tid & 63;
    __shared__ float hss[8];
    __shared__ float red[4];
    float y[4];
    if (tid < 8) hss[tid] = 0.f;
    __syncthreads();
#pragma unroll
    for (int k = 0; k < 4; ++k) {
        int p = k * 256 + tid;
        const size_t jS = (size_t)128 * DD;
        size_t base = (size_t)row * DD + p;
        y[k] = ypp[base] + ypp[base + jS] + ypp[base + 2 * jS] + ypp[base + 3 * jS];
        float s = y[k] * y[k];
#pragma unroll
        for (int off = 32; off; off >>= 1) s += __shfl_down(s, off);
        if (lane == 0) atomicAdd(&hss[(k * 256 + w * 64) >> 7], s);
    }
    __syncthreads();
    float val = 0.f;
#pragma unroll
    for (int k = 0; k < 4; ++k) {
        int p = k * 256 + tid;
        int hh = p >> 7, e = p & 127;
        float rs = rsqrtf(hss[hh] * (1.f / 128.f) + EPS_);
        val += y[k] * rs * rms_w[e] * (1.f - LAMBDA_INIT) * woh[p];
    }
#pragma unroll
    for (int off = 32; off; off >>= 1) val += __shfl_down(val, off);
    if (lane == 0) red[w] = val;
    __syncthreads();
    if (tid == 0) logits[row] = red[0] + red[1] + red[2] + red[3];
}

extern "C" void kernel_launch(void* const* d_in, const int* in_sizes, int n_in,
                              void* d_out, int out_size, void* d_ws, size_t ws_size,
                              hipStream_t stream) {
    (void)in_sizes; (void)n_in; (void)out_size; (void)ws_size;
    const float* x       = (const float*)d_in[0];
    const float* atlas_q = (const float*)d_in[1];
    const float* Wq      = (const float*)d_in[2];
    const float* Wk      = (const float*)d_in[3];
    const float* Wv      = (const float*)d_in[4];
    const float* Wo      = (const float*)d_in[5];
    const float* rms_w   = (const float*)d_in[6];
    const float* Whead   = (const float*)d_in[7];
    const float* lq1     = (const float*)d_in[8];
    const float* lk1     = (const float*)d_in[9];
    const float* lq2     = (const float*)d_in[10];
    const float* lk2     = (const float*)d_in[11];
    float* out = (float*)d_out;
    float* ws  = (float*)d_ws;

    float*  qprojp = ws + OFF_QPROJP;
    ushort* M2     = (ushort*)(ws + OFF_M2);
    float*  lam    = ws + OFF_LAM;
    float*  woh    = ws + OFF_WOH;
    float*  scores = ws + OFF_SC;
    float*  aggp   = ws + OFF_SC;      // reuse: scores dead after k_softdiff
    ushort* diffb  = (ushort*)(ws + OFF_DIFFB);
    float*  ypp    = ws + OFF_DIFFB;   // reuse: diffb dead after k_agg

    hipLaunchKernelGGL(k_setup,    dim3(193),        dim3(256), 0, stream,
                       atlas_q, Wq, Wo, Whead, lq1, lk1, lq2, lk2, qprojp, woh, lam);
    hipLaunchKernelGGL(k_m2,       dim3(512),        dim3(256), 0, stream, qprojp, Wk, M2);
    hipLaunchKernelGGL(k_scores,   dim3(16, 32),     dim3(256), 0, stream, x, M2, scores);
    hipLaunchKernelGGL(k_softdiff, dim3(1024),       dim3(256), 0, stream, scores, lam, diffb);
    hipLaunchKernelGGL(k_agg,      dim3(16, 16, 4),  dim3(256), 0, stream, x, diffb, aggp);
    hipLaunchKernelGGL(k_yp,       dim3(8, 16, 4),   dim3(256), 0, stream, aggp, Wv, ypp);
    hipLaunchKernelGGL(k_logits,   dim3(128),        dim3(256), 0, stream, ypp, rms_w, woh, out);
}